// Round 2
// baseline (659.372 us; speedup 1.0000x reference)
//
#include <hip/hip_runtime.h>
#include <stdint.h>

#define NB_    20000
#define CB_    128
#define EE_    320000
#define BN_    40000            // B*N
#define BE_    640000           // B*E
#define ETOT_  680000           // BE_ + BN_

typedef __attribute__((ext_vector_type(4))) float f4;
typedef __attribute__((ext_vector_type(4))) unsigned short us4;
typedef __attribute__((ext_vector_type(4))) unsigned int ui4;
typedef __attribute__((ext_vector_type(8))) __bf16 bf16x8;

static __device__ __forceinline__ unsigned short f2bf(float f){
    union { float f; unsigned int u; } v; v.f = f;
    unsigned int u = v.u;
    u += 0x7FFFu + ((u >> 16) & 1u);
    return (unsigned short)(u >> 16);
}
static __device__ __forceinline__ float bf2f(unsigned short b){
    union { unsigned int u; float f; } v; v.u = ((unsigned int)b) << 16;
    return v.f;
}
static __device__ __forceinline__ float sigf(float x){ return 1.f/(1.f+__expf(-x)); }
static __device__ __forceinline__ float tanhfast(float x){ return 2.f/(1.f+__expf(-2.f*x)) - 1.f; }

static __device__ __forceinline__ void glds16(const unsigned short* g, unsigned short* l){
    __builtin_amdgcn_global_load_lds(
        (const __attribute__((address_space(1))) void*)g,
        (__attribute__((address_space(3))) void*)l, 16, 0, 0);
}

// ---------------- fused pack kernel ----------------
// blocks [0,2304): LSTM W repack to fragment order [l][jb][kt][n][lane][8]
// blocks [2304,2432): lin_w transpose->bf16
// blocks [2432,2589): zero deg
// block  2589: W2 (fold lin_edge_w with att_edge)
// blocks [2590,2602): combined bias
__global__ __launch_bounds__(256) void pack_kernel(const float* __restrict__ lw,
        const float* __restrict__ lew, const float* __restrict__ ae,
        const float* __restrict__ w_ih, const float* __restrict__ b_ih, const float* __restrict__ b_hh,
        unsigned short* __restrict__ lwT, unsigned short* __restrict__ Bp,
        float* __restrict__ bsum, float* __restrict__ W2, int* __restrict__ deg){
    int b = blockIdx.x, t = threadIdx.x;
    if (b < 2304) {
        int tid = b*256 + t;                 // < 589824
        int idx = tid;
        int e = idx & 7;  idx >>= 3;
        int lane = idx & 63; idx >>= 6;
        int n = idx % 12; idx /= 12;
        int kt = idx & 7; idx >>= 3;
        int jb = idx & 3; int l = idx >> 2;
        int wn = n / 6, rem = n - wn*6, gate = rem >> 1, jg = rem & 1;
        int gor = (gate == 0) ? 0 : (gate == 1 ? 2 : 3);   // i,g,o -> rows i,f,g,o
        int row = gor*256 + jb*64 + wn*32 + jg*16 + (lane & 15);
        int k = kt*32 + (lane >> 4)*8 + e;
        Bp[tid] = f2bf(w_ih[(l*1024 + row)*256 + k]);
    } else if (b < 2432) {
        int tid = (b-2304)*256 + t;          // 32768
        int nn = tid >> 7, k = tid & 127;
        lwT[nn*128 + k] = f2bf(lw[k*256 + nn]);
    } else if (b < 2589) {
        int i = (b-2432)*256 + t;
        if (i < BN_) deg[i] = 0;
    } else if (b == 2589) {
        if (t < 64) {
            int dd = t >> 2, h = t & 3;
            float s = 0.f;
            for (int c = 0; c < 64; ++c) s += lew[dd*256 + h*64 + c] * ae[h*64 + c];
            W2[dd*4 + h] = s;
        }
    } else {
        int i = (b-2590)*256 + t;
        if (i < 3072) bsum[i] = b_ih[i] + b_hh[i];
    }
}

// ---------------- GEMM1: xt[40000,256] = x[40000,128] @ lin_w  (bf16 MFMA) ----------------
__global__ __launch_bounds__(256) void gemm1_kernel(const float* __restrict__ x,
        const unsigned short* __restrict__ wt, unsigned short* __restrict__ xt){
    __shared__ unsigned short As[64*72];
    __shared__ unsigned short Bs[64*72];
    const int tid = threadIdx.x;
    const int bm = blockIdx.x, bn = blockIdx.y;
    const int lane = tid & 63, w = tid >> 6;
    const int wm = w & 1, wn = w >> 1;
    const int nl = lane & 15, q = lane >> 4;
    f4 acc[2][2] = {};
    for (int kc = 0; kc < 128; kc += 64) {
        #pragma unroll
        for (int it = 0; it < 4; ++it) {
            int s = tid + it*256;
            int row = s >> 4, c4 = s & 15;
            f4 v = *(const f4*)&x[(bm*64+row)*128 + kc + c4*4];
            us4 o; o[0]=f2bf(v[0]); o[1]=f2bf(v[1]); o[2]=f2bf(v[2]); o[3]=f2bf(v[3]);
            *(us4*)&As[row*72 + c4*4] = o;
        }
        #pragma unroll
        for (int it = 0; it < 2; ++it) {
            int s = tid + it*256;
            int row = s >> 3, c = s & 7;
            *(ui4*)&Bs[row*72 + c*8] = *(const ui4*)&wt[(bn*64+row)*128 + kc + c*8];
        }
        __syncthreads();
        #pragma unroll
        for (int kk = 0; kk < 64; kk += 32) {
            bf16x8 a[2], b[2];
            #pragma unroll
            for (int mt = 0; mt < 2; ++mt) a[mt] = *(const bf16x8*)&As[(wm*32 + mt*16 + nl)*72 + kk + q*8];
            #pragma unroll
            for (int nt = 0; nt < 2; ++nt) b[nt] = *(const bf16x8*)&Bs[(wn*32 + nt*16 + nl)*72 + kk + q*8];
            #pragma unroll
            for (int mt = 0; mt < 2; ++mt)
                #pragma unroll
                for (int nt = 0; nt < 2; ++nt)
                    acc[mt][nt] = __builtin_amdgcn_mfma_f32_16x16x32_bf16(a[mt], b[nt], acc[mt][nt], 0, 0, 0);
        }
        __syncthreads();
    }
    #pragma unroll
    for (int mt = 0; mt < 2; ++mt)
        #pragma unroll
        for (int nt = 0; nt < 2; ++nt)
            #pragma unroll
            for (int r = 0; r < 4; ++r) {
                int row = bm*64 + wm*32 + mt*16 + q*4 + r;
                int col = bn*64 + wn*32 + nt*16 + nl;
                xt[row*256 + col] = f2bf(acc[mt][nt][r]);
            }
}

// ---------------- per-node attention scores ----------------
__global__ __launch_bounds__(256) void scores_kernel(const unsigned short* __restrict__ xt,
        const float* __restrict__ att_src, const float* __restrict__ att_dst,
        float* __restrict__ s_src, float* __restrict__ s_dst){
    int n = blockIdx.x*4 + (threadIdx.x >> 6);
    int lane = threadIdx.x & 63;
    us4 xv = *(const us4*)&xt[n*256 + lane*4];
    f4 as = *(const f4*)&att_src[lane*4];
    f4 ad = *(const f4*)&att_dst[lane*4];
    float x0=bf2f(xv[0]), x1=bf2f(xv[1]), x2=bf2f(xv[2]), x3=bf2f(xv[3]);
    float ps = x0*as[0]+x1*as[1]+x2*as[2]+x3*as[3];
    float pd = x0*ad[0]+x1*ad[1]+x2*ad[2]+x3*ad[3];
    #pragma unroll
    for (int o = 1; o < 16; o <<= 1) { ps += __shfl_xor(ps, o, 64); pd += __shfl_xor(pd, o, 64); }
    if ((lane & 15) == 0) {
        s_src[n*4 + (lane>>4)] = ps;
        s_dst[n*4 + (lane>>4)] = pd;
    }
}

// ---------------- edge scores: esc[E,4] = edge_attr[E,16] @ W2[16,4] ----------------
__global__ __launch_bounds__(256) void eascore_kernel(const float* __restrict__ ea,
        const float* __restrict__ W2, float* __restrict__ esc){
    __shared__ float w2s[64];
    if (threadIdx.x < 64) w2s[threadIdx.x] = W2[threadIdx.x];
    __syncthreads();
    int e = blockIdx.x*256 + threadIdx.x;
    if (e >= EE_) return;
    f4 acc = {};
    #pragma unroll
    for (int d = 0; d < 16; ++d) {
        float v = ea[e*16 + d];
        f4 wv = *(const f4*)&w2s[d*4];
        acc += v * wv;
    }
    *(f4*)&esc[e*4] = acc;
}

// ---------------- CSR build ----------------
__global__ __launch_bounds__(256) void deghist_kernel(const int* __restrict__ ei, int* __restrict__ deg){
    int e = blockIdx.x*256 + threadIdx.x;
    if (e >= ETOT_) return;
    int dst;
    if (e < BE_) { int b = e / EE_, ee = e - b*EE_; dst = ei[EE_ + ee] + b*NB_; }
    else dst = e - BE_;
    atomicAdd(&deg[dst], 1);
}

__global__ __launch_bounds__(256) void scan1_kernel(const int* __restrict__ deg,
        int* __restrict__ inc, int* __restrict__ bsumc){
    __shared__ int sd[256];
    int t = threadIdx.x, i = blockIdx.x*256 + t;
    int v = (i < BN_) ? deg[i] : 0;
    sd[t] = v; __syncthreads();
    #pragma unroll
    for (int d = 1; d < 256; d <<= 1) {
        int x = (t >= d) ? sd[t-d] : 0; __syncthreads();
        sd[t] += x; __syncthreads();
    }
    inc[i] = sd[t];
    if (t == 255) bsumc[blockIdx.x] = sd[255];
}

__global__ __launch_bounds__(256) void scan2_kernel(const int* __restrict__ bsumc,
        int* __restrict__ bpre, int nb){
    __shared__ int sd[256];
    int t = threadIdx.x;
    int v = (t < nb) ? bsumc[t] : 0;
    sd[t] = v; __syncthreads();
    #pragma unroll
    for (int d = 1; d < 256; d <<= 1) {
        int x = (t >= d) ? sd[t-d] : 0; __syncthreads();
        sd[t] += x; __syncthreads();
    }
    if (t < nb) bpre[t] = sd[t] - v;
}

__global__ __launch_bounds__(256) void scan3_kernel(const int* __restrict__ inc,
        const int* __restrict__ deg, const int* __restrict__ bpre,
        int* __restrict__ offs, int* __restrict__ cur){
    int i = blockIdx.x*256 + threadIdx.x;
    if (i >= BN_) return;
    int o = inc[i] - deg[i] + bpre[blockIdx.x];
    offs[i] = o; cur[i] = o;
}

// scatter: compute e = exp(leaky(alpha)) directly (no max-subtract needed: |alpha|<~15)
__global__ __launch_bounds__(256) void scatter_kernel(const int* __restrict__ ei,
        const float* __restrict__ s_src, const float* __restrict__ s_dst,
        const float* __restrict__ esc, int* __restrict__ cur,
        int* __restrict__ csr_src, float* __restrict__ csr_e){
    int e = blockIdx.x*256 + threadIdx.x;
    if (e >= ETOT_) return;
    int src, dst; f4 a;
    if (e < BE_) {
        int b = e / EE_, ee = e - b*EE_;
        src = ei[ee] + b*NB_;
        dst = ei[EE_ + ee] + b*NB_;
        a = *(const f4*)&esc[ee*4];
    } else {
        src = dst = e - BE_;
        a = (f4){0.f, 0.f, 0.f, 0.f};
    }
    a += *(const f4*)&s_src[src*4];
    a += *(const f4*)&s_dst[dst*4];
    #pragma unroll
    for (int h = 0; h < 4; ++h) {
        float v = a[h];
        v = (v > 0.f) ? v : 0.2f*v;
        a[h] = __expf(v);
    }
    int pos = atomicAdd(&cur[dst], 1);
    csr_src[pos] = src;
    *(f4*)&csr_e[pos*4] = a;
}

// ---------------- segment softmax + aggregate: one wave per node, 2 passes ----------------
__global__ __launch_bounds__(256) void aggregate_kernel(const int* __restrict__ offs,
        const int* __restrict__ deg, const int* __restrict__ csr_src,
        const float* __restrict__ csr_e, const unsigned short* __restrict__ xt,
        const float* __restrict__ gat_bias, unsigned short* __restrict__ spat){
    int n = blockIdx.x*4 + (threadIdx.x >> 6);
    int lane = threadIdx.x & 63;
    int start = offs[n], d = deg[n];
    // pass 1: sums
    f4 sv = {};
    for (int i = lane; i < d; i += 64) sv += *(const f4*)&csr_e[(start+i)*4];
    #pragma unroll
    for (int o = 1; o < 64; o <<= 1) {
        sv[0]+=__shfl_xor(sv[0],o,64); sv[1]+=__shfl_xor(sv[1],o,64);
        sv[2]+=__shfl_xor(sv[2],o,64); sv[3]+=__shfl_xor(sv[3],o,64);
    }
    int h = lane >> 4;
    float sh = (h==0)?sv[0]:(h==1)?sv[1]:(h==2)?sv[2]:sv[3];
    float inv = 1.f / (sh + 1e-16f);
    // pass 2: gather, 4-way unrolled for MLP
    const float* eh = csr_e + h;
    f4 accv = {};
    for (int base = 0; base < d; base += 64) {
        int cnt = min(64, d - base);
        int srcl = (base + lane < d) ? csr_src[start+base+lane] : 0;
        int i = 0;
        for (; i + 4 <= cnt; i += 4) {
            int p = start + base + i;
            int s0=__shfl(srcl,i,64), s1=__shfl(srcl,i+1,64), s2=__shfl(srcl,i+2,64), s3=__shfl(srcl,i+3,64);
            float e0=eh[p*4], e1=eh[(p+1)*4], e2=eh[(p+2)*4], e3=eh[(p+3)*4];
            us4 x0=*(const us4*)&xt[s0*256 + lane*4];
            us4 x1=*(const us4*)&xt[s1*256 + lane*4];
            us4 x2=*(const us4*)&xt[s2*256 + lane*4];
            us4 x3=*(const us4*)&xt[s3*256 + lane*4];
            accv[0] += e0*bf2f(x0[0]) + e1*bf2f(x1[0]) + e2*bf2f(x2[0]) + e3*bf2f(x3[0]);
            accv[1] += e0*bf2f(x0[1]) + e1*bf2f(x1[1]) + e2*bf2f(x2[1]) + e3*bf2f(x3[1]);
            accv[2] += e0*bf2f(x0[2]) + e1*bf2f(x1[2]) + e2*bf2f(x2[2]) + e3*bf2f(x3[2]);
            accv[3] += e0*bf2f(x0[3]) + e1*bf2f(x1[3]) + e2*bf2f(x2[3]) + e3*bf2f(x3[3]);
        }
        for (; i < cnt; ++i) {
            int p = start + base + i;
            int s0 = __shfl(srcl, i, 64);
            float e0 = eh[p*4];
            us4 x0 = *(const us4*)&xt[s0*256 + lane*4];
            accv[0] += e0*bf2f(x0[0]); accv[1] += e0*bf2f(x0[1]);
            accv[2] += e0*bf2f(x0[2]); accv[3] += e0*bf2f(x0[3]);
        }
    }
    f4 gb = *(const f4*)&gat_bias[lane*4];
    accv = accv * inv + gb;
    us4 o4; o4[0]=f2bf(accv[0]); o4[1]=f2bf(accv[1]); o4[2]=f2bf(accv[2]); o4[3]=f2bf(accv[3]);
    *(us4*)&spat[n*256 + lane*4] = o4;
}

// ---------------- LSTM layer v2: global_load_lds staging, fragment-tiled LDS ----------------
// block: 256 thr, tile M=128 x Npacked=192 (jb: 64 j-cols x {i,g,o}); wave tile 64x96.
// LDS: A frags [rt0..7][ktl0..1] (16 x 1KB) then B frags [ktl0..1][n0..11] (24 x 1KB).
__global__ __launch_bounds__(256) void lstm2_kernel(const unsigned short* __restrict__ A,
        const unsigned short* __restrict__ Bp, const float* __restrict__ bsum,
        float* __restrict__ hs_out, float* __restrict__ cs_out,
        unsigned short* __restrict__ hnext){
    __shared__ unsigned short lds[40*512];
    const int tid = threadIdx.x;
    const int lane = tid & 63, w = tid >> 6;
    const int bm = blockIdx.x, jb = blockIdx.y;
    const int wm = w & 1, wn = w >> 1;
    const int nl = lane & 15, q = lane >> 4;
    f4 acc[4][6] = {};
    // per-lane global A base: row = bm*128 + rt*16 + nl, colchunk q*8
    const unsigned short* Abase = A + (size_t)(bm*128 + nl)*256 + q*8;
    const unsigned short* Bjb = Bp + jb*(8*12*512);
    for (int kci = 0; kci < 4; ++kci) {
        const int kc = kci*64;
        // stage A: wave w -> rt {2w, 2w+1} x ktl {0,1}
        #pragma unroll
        for (int f = 0; f < 4; ++f) {
            int rt = w*2 + (f >> 1), ktl = f & 1;
            glds16(Abase + rt*16*256 + kc + ktl*32, &lds[(rt*2 + ktl)*512]);
        }
        // stage B: wave w -> n {3w..3w+2} x ktl {0,1}; Bp already in frag order
        const unsigned short* Bk = Bjb + (size_t)(kci*2)*12*512 + lane*8;
        #pragma unroll
        for (int f = 0; f < 6; ++f) {
            int ktl = (f >= 3) ? 1 : 0;
            int nn = w*3 + (ktl ? f-3 : f);
            glds16(Bk + (ktl*12 + nn)*512, &lds[(16 + ktl*12 + nn)*512]);
        }
        __syncthreads();
        #pragma unroll
        for (int ktl = 0; ktl < 2; ++ktl) {
            bf16x8 af[4], bfr[6];
            #pragma unroll
            for (int mt = 0; mt < 4; ++mt)
                af[mt] = *(const bf16x8*)&lds[((wm*4 + mt)*2 + ktl)*512 + lane*8];
            #pragma unroll
            for (int nt = 0; nt < 6; ++nt)
                bfr[nt] = *(const bf16x8*)&lds[(16 + ktl*12 + wn*6 + nt)*512 + lane*8];
            #pragma unroll
            for (int mt = 0; mt < 4; ++mt)
                #pragma unroll
                for (int nt = 0; nt < 6; ++nt)
                    acc[mt][nt] = __builtin_amdgcn_mfma_f32_16x16x32_bf16(af[mt], bfr[nt], acc[mt][nt], 0, 0, 0);
        }
        __syncthreads();
    }
    // epilogue: wave owns j-cols jb*64 + wn*32 + jg*16 + nl, gates i,g,o coupled in-register
    const int jbase = jb*64 + wn*32;
    #pragma unroll
    for (int jg = 0; jg < 2; ++jg) {
        const int j = jbase + jg*16 + nl;
        const float bi = bsum[j];           // i rows 0..255
        const float bg = bsum[512 + j];     // g rows 512..767
        const float bo = bsum[768 + j];     // o rows 768..1023
        #pragma unroll
        for (int mt = 0; mt < 4; ++mt)
            #pragma unroll
            for (int r = 0; r < 4; ++r) {
                int m = bm*128 + wm*64 + mt*16 + q*4 + r;
                if (m < BN_) {
                    float iv = acc[mt][0 + jg][r] + bi;
                    float gv = acc[mt][2 + jg][r] + bg;
                    float ov = acc[mt][4 + jg][r] + bo;
                    float c  = sigf(iv) * tanhfast(gv);
                    float hh = sigf(ov) * tanhfast(c);
                    cs_out[m*256 + j] = c;
                    hs_out[m*256 + j] = hh;
                    if (hnext) hnext[m*256 + j] = f2bf(hh);
                }
            }
    }
}

// ---------------- LayerNorm ----------------
__global__ __launch_bounds__(256) void ln_kernel(const float* __restrict__ hin,
        const float* __restrict__ g, const float* __restrict__ b, float* __restrict__ out){
    int n = blockIdx.x*4 + (threadIdx.x >> 6);
    int lane = threadIdx.x & 63;
    f4 v = *(const f4*)&hin[n*256 + lane*4];
    float s = v[0]+v[1]+v[2]+v[3];
    float ss = v[0]*v[0]+v[1]*v[1]+v[2]*v[2]+v[3]*v[3];
    #pragma unroll
    for (int o = 1; o < 64; o <<= 1) { s += __shfl_xor(s,o,64); ss += __shfl_xor(ss,o,64); }
    float mu = s * (1.f/256.f);
    float var = ss * (1.f/256.f) - mu*mu;
    float rstd = rsqrtf(var + 1e-5f);
    f4 gg = *(const f4*)&g[lane*4], bb = *(const f4*)&b[lane*4];
    f4 o4 = (v - mu) * rstd * gg + bb;
    *(f4*)&out[n*256 + lane*4] = o4;
}

// ---------------- host ----------------
static inline char* carve(char*& p, size_t bytes){
    char* r = p; p += (bytes + 255) & ~(size_t)255; return r;
}

extern "C" void kernel_launch(void* const* d_in, const int* in_sizes, int n_in,
                              void* d_out, int out_size, void* d_ws, size_t ws_size,
                              hipStream_t stream){
    const float* x         = (const float*)d_in[0];
    const int*   ei        = (const int*)  d_in[1];
    const float* edge_attr = (const float*)d_in[2];
    const float* lin_w     = (const float*)d_in[3];
    const float* att_src   = (const float*)d_in[4];
    const float* att_dst   = (const float*)d_in[5];
    const float* lin_edge_w= (const float*)d_in[6];
    const float* att_edge  = (const float*)d_in[7];
    const float* gat_bias  = (const float*)d_in[8];
    const float* w_ih      = (const float*)d_in[9];
    const float* b_ih      = (const float*)d_in[11];
    const float* b_hh      = (const float*)d_in[12];
    const float* ln_g      = (const float*)d_in[13];
    const float* ln_b      = (const float*)d_in[14];

    float* out = (float*)d_out;
    float* hs_base = out + 10240000;          // [3][40000][256]
    float* cs_base = out + 40960000;          // [3][40000][256]

    // scratch aliased into d_out (liveness verified; see round-1 notes)
    unsigned short* xt   = (unsigned short*)(out + 0);          // dead after aggregate
    float* esc           = out + 10240000;                       // dead before lstm0 writes hs[0]
    int*   csr_src       = (int*)(out + 40960000);               // dead before lstm0 writes cs[0]
    float* csr_e         = out + 41640000;                       // ditto
    unsigned short* spat = (unsigned short*)(out + 51200000);    // in cs[1], dead before lstm1
    unsigned short* h0   = (unsigned short*)(out + 61440000);    // in cs[2], dead before lstm2
    unsigned short* h1   = (unsigned short*)(out + 0);           // reuse xt region

    char* p = (char*)d_ws;
    float* W2          = (float*)carve(p, 64*4);
    float* s_src       = (float*)carve(p, (size_t)BN_*4*4);
    float* s_dst       = (float*)carve(p, (size_t)BN_*4*4);
    unsigned short* lwT= (unsigned short*)carve(p, 32768*2);
    unsigned short* Bp = (unsigned short*)carve(p, 589824*2);
    float* bsum        = (float*)carve(p, 3072*4);
    int* deg           = (int*)carve(p, BN_*4);
    int* inc           = (int*)carve(p, 157*256*4);
    int* bsumc         = (int*)carve(p, 256*4);
    int* bpre          = (int*)carve(p, 256*4);
    int* offs          = (int*)carve(p, BN_*4);
    int* cur           = (int*)carve(p, BN_*4);

    pack_kernel<<<2602, 256, 0, stream>>>(lin_w, lin_edge_w, att_edge, w_ih, b_ih, b_hh,
                                          lwT, Bp, bsum, W2, deg);

    gemm1_kernel<<<dim3(625, 4), 256, 0, stream>>>(x, lwT, xt);
    scores_kernel<<<10000, 256, 0, stream>>>(xt, att_src, att_dst, s_src, s_dst);
    eascore_kernel<<<1250, 256, 0, stream>>>(edge_attr, W2, esc);

    deghist_kernel<<<2657, 256, 0, stream>>>(ei, deg);
    scan1_kernel<<<157, 256, 0, stream>>>(deg, inc, bsumc);
    scan2_kernel<<<1, 256, 0, stream>>>(bsumc, bpre, 157);
    scan3_kernel<<<157, 256, 0, stream>>>(inc, deg, bpre, offs, cur);
    scatter_kernel<<<2657, 256, 0, stream>>>(ei, s_src, s_dst, esc, cur, csr_src, csr_e);
    aggregate_kernel<<<10000, 256, 0, stream>>>(offs, deg, csr_src, csr_e, xt, gat_bias, spat);

    lstm2_kernel<<<dim3(313, 4), 256, 0, stream>>>(spat, Bp,          bsum,        hs_base,            cs_base,            h0);
    lstm2_kernel<<<dim3(313, 4), 256, 0, stream>>>(h0,   Bp + 196608, bsum + 1024, hs_base + 10240000, cs_base + 10240000, h1);
    lstm2_kernel<<<dim3(313, 4), 256, 0, stream>>>(h1,   Bp + 393216, bsum + 2048, hs_base + 20480000, cs_base + 20480000, (unsigned short*)nullptr);

    ln_kernel<<<10000, 256, 0, stream>>>(hs_base + 20480000, ln_g, ln_b, out);
}